// Round 1
// baseline (311.009 us; speedup 1.0000x reference)
//
#include <hip/hip_runtime.h>
#include <hip/hip_bf16.h>

// PrimaryCaps fused 1x1 convs -> batched GEMM:
//   per n: Out[544,1024] = W[544,512] * X_n[512,1024]
//   rows 0..511  -> poses   (+ b_pose)
//   rows 512..543-> sigmoid (+ b_act) into the activations region
// bf16 MFMA (16x16x32), fp32 accumulate. x/W are fp32 in global; convert to
// bf16 during staging. X tile is transposed in LDS ([m][k]) so both MFMA
// operands are k-contiguous -> ds_read_b128 frag loads.

typedef __attribute__((ext_vector_type(8))) short short8;
typedef __attribute__((ext_vector_type(4))) float f32x4;

#define A_CH   512
#define HW     1024
#define N_B    64
#define O_POSE 512
#define O_ACT  32
#define O_TOT  544
#define TILE   128
#define BK     32

__device__ __forceinline__ unsigned pack_bf16x2(float lo, float hi) {
    __hip_bfloat162 h = __float22bfloat162_rn(make_float2(lo, hi));
    return *reinterpret_cast<unsigned*>(&h);
}

__global__ __launch_bounds__(256) void caps_fused_gemm(
    const float* __restrict__ x,   // [64,512,32,32]
    const float* __restrict__ Wp,  // [512,512]
    const float* __restrict__ bp,  // [512]
    const float* __restrict__ Wa,  // [32,512]
    const float* __restrict__ ba,  // [32]
    float* __restrict__ out)       // poses [64,512,1024] ++ act [64,32,1024]
{
    // bf16 tiles, [row][k] with XOR swizzle k' = k ^ (8*((row>>1)&3)).
    // Reads (b128, 8 bf16 along k): <=2 lanes/bank -> conflict-free.
    __shared__ __align__(16) short ldsA[TILE * BK];  // W tile  [o][k]
    __shared__ __align__(16) short ldsB[TILE * BK];  // X tile  [m][k] (transposed)

    const int tid = threadIdx.x;
    const int n   = blockIdx.z;
    const int o0  = blockIdx.y * TILE;   // 0,128,256,384,512
    const int m0  = blockIdx.x * TILE;

    const float* xn = x + (size_t)n * A_CH * HW + m0;

    // B staging map: m = tid&127 (lane-consecutive -> coalesced), k-half = tid>>7
    const int bm  = tid & 127;
    const int bkh = (tid >> 7) * 16;

    float4 a_reg[4];
    float  b_reg[4][4];

    auto load_tiles = [&](int k0) {
        // A: lin = tid + 256c -> o = lin>>3, kc = lin&7 (8 float4 chunks/row)
#pragma unroll
        for (int c = 0; c < 4; ++c) {
            int lin = tid + 256 * c;
            int o = lin >> 3, kc = lin & 7;
            int R = o0 + o;
            float4 v = make_float4(0.f, 0.f, 0.f, 0.f);
            if (R < O_POSE)     v = *(const float4*)(Wp + (size_t)R * A_CH + k0 + kc * 4);
            else if (R < O_TOT) v = *(const float4*)(Wa + (size_t)(R - O_POSE) * A_CH + k0 + kc * 4);
            a_reg[c] = v;
        }
        // B: 4 chunks of 4 k-rows, one m each (k-column -> transpose in regs)
#pragma unroll
        for (int c = 0; c < 4; ++c) {
            int kb = k0 + bkh + c * 4;
#pragma unroll
            for (int j = 0; j < 4; ++j)
                b_reg[c][j] = xn[(size_t)(kb + j) * HW + bm];
        }
    };

    auto store_tiles = [&]() {
#pragma unroll
        for (int c = 0; c < 4; ++c) {
            int lin = tid + 256 * c;
            int o = lin >> 3, kc = lin & 7;
            int kx = (kc * 4) ^ (8 * ((o >> 1) & 3));
            uint2 p;
            p.x = pack_bf16x2(a_reg[c].x, a_reg[c].y);
            p.y = pack_bf16x2(a_reg[c].z, a_reg[c].w);
            *(uint2*)&ldsA[o * BK + kx] = p;
        }
#pragma unroll
        for (int c = 0; c < 4; ++c) {
            int kloc = bkh + c * 4;
            int kx = kloc ^ (8 * ((bm >> 1) & 3));
            uint2 p;
            p.x = pack_bf16x2(b_reg[c][0], b_reg[c][1]);
            p.y = pack_bf16x2(b_reg[c][2], b_reg[c][3]);
            *(uint2*)&ldsB[bm * BK + kx] = p;
        }
    };

    // wave -> 64x64 quadrant; 4x4 frags of 16x16x32
    const int lane = tid & 63;
    const int w    = tid >> 6;
    const int wo   = (w >> 1) * 64;
    const int wm   = (w & 1) * 64;
    const int l16  = lane & 15;
    const int g    = lane >> 4;

    f32x4 acc[4][4] = {};  // [fo][fm]

    load_tiles(0);

    for (int it = 0; it < A_CH / BK; ++it) {
        __syncthreads();
        store_tiles();
        __syncthreads();
        if (it + 1 < A_CH / BK) load_tiles((it + 1) * BK);  // prefetch in flight under MFMA

        short8 aF[4], bF[4];
#pragma unroll
        for (int f = 0; f < 4; ++f) {
            int r  = wo + f * 16 + l16;
            int kx = (g * 8) ^ (8 * ((r >> 1) & 3));
            aF[f] = *(const short8*)&ldsA[r * BK + kx];
            int cC  = wm + f * 16 + l16;
            int kxb = (g * 8) ^ (8 * ((cC >> 1) & 3));
            bF[f] = *(const short8*)&ldsB[cC * BK + kxb];
        }
#pragma unroll
        for (int fo = 0; fo < 4; ++fo)
#pragma unroll
            for (int fm = 0; fm < 4; ++fm)
                acc[fo][fm] = __builtin_amdgcn_mfma_f32_16x16x32_bf16(
                    aF[fo], bF[fm], acc[fo][fm], 0, 0, 0);
    }

    // epilogue: C/D layout col = lane&15, row = (lane>>4)*4 + reg
    float* actOut = out + (size_t)N_B * O_POSE * HW;
    const size_t poseN = (size_t)n * O_POSE * HW;
    const size_t actN  = (size_t)n * O_ACT * HW;
#pragma unroll
    for (int fo = 0; fo < 4; ++fo) {
#pragma unroll
        for (int i = 0; i < 4; ++i) {
            int R = o0 + wo + fo * 16 + g * 4 + i;
            if (R >= O_TOT) continue;
            if (R < O_POSE) {
                float bias = bp[R];
#pragma unroll
                for (int fm = 0; fm < 4; ++fm) {
                    int cc = m0 + wm + fm * 16 + l16;
                    out[poseN + (size_t)R * HW + cc] = acc[fo][fm][i] + bias;
                }
            } else {
                float bias = ba[R - O_POSE];
#pragma unroll
                for (int fm = 0; fm < 4; ++fm) {
                    int cc = m0 + wm + fm * 16 + l16;
                    float v = acc[fo][fm][i] + bias;
                    actOut[actN + (size_t)(R - O_POSE) * HW + cc] = 1.0f / (1.0f + __expf(-v));
                }
            }
        }
    }
}

extern "C" void kernel_launch(void* const* d_in, const int* in_sizes, int n_in,
                              void* d_out, int out_size, void* d_ws, size_t ws_size,
                              hipStream_t stream) {
    (void)in_sizes; (void)n_in; (void)d_ws; (void)ws_size; (void)out_size;
    const float* x  = (const float*)d_in[0];
    const float* Wp = (const float*)d_in[1];
    const float* bp = (const float*)d_in[2];
    const float* Wa = (const float*)d_in[3];
    const float* ba = (const float*)d_in[4];
    // grid: x = m-tiles (8), y = o-tiles (5), z = n (64).
    // The 5 o-tiles sharing one x-strip differ by exactly 8 in linear block id
    // -> same XCD (id%8 heuristic) -> L2 absorbs the x re-reads.
    dim3 grid(HW / TILE, (O_TOT + TILE - 1) / TILE, N_B);
    caps_fused_gemm<<<grid, dim3(256), 0, stream>>>(x, Wp, bp, Wa, ba, (float*)d_out);
}

// Round 2
// 291.289 us; speedup vs baseline: 1.0677x; 1.0677x over previous
//
#include <hip/hip_runtime.h>
#include <hip/hip_bf16.h>

// PrimaryCaps fused 1x1 convs -> batched GEMM:
//   per n: Out[544,1024] = W[544,512] * X_n[512,1024]
// bf16 MFMA 16x16x32, fp32 accumulate. fp32->bf16 on the fly during staging.
// R2: single-barrier K-loop with LDS double-buffer, 512-thr blocks
// (128o x 256m tile, 8 waves), b128 LDS writes, nontemporal output stores.

typedef __attribute__((ext_vector_type(8))) short short8;
typedef __attribute__((ext_vector_type(4))) float f32x4;

#define A_CH   512
#define HW     1024
#define N_B    64
#define O_POSE 512
#define O_ACT  32
#define O_TOT  544
#define TO     128
#define TM     256
#define BK     32
#define NIT    (A_CH / BK)   // 16

__device__ __forceinline__ unsigned pk(float lo, float hi) {
    __hip_bfloat162 h = __float22bfloat162_rn(make_float2(lo, hi));
    return *reinterpret_cast<unsigned*>(&h);
}

__global__ __launch_bounds__(512, 4) void caps_fused_gemm(
    const float* __restrict__ x,   // [64,512,32,32]
    const float* __restrict__ Wp,  // [512,512]
    const float* __restrict__ bp,  // [512]
    const float* __restrict__ Wa,  // [32,512]
    const float* __restrict__ ba,  // [32]
    float* __restrict__ out)       // poses [64,512,1024] ++ act [64,32,1024]
{
    // bf16 [row][k] tiles, swizzle k' = k ^ (8*((row>>1)&3)), 8-aligned ->
    // b128 reads/writes stay 16B-atomic; frag reads <=2 lanes/bank (free).
    __shared__ __align__(16) short ldsA[2][TO * BK];  // W tile  16 KB
    __shared__ __align__(16) short ldsB[2][TM * BK];  // X tile  32 KB

    const int tid = threadIdx.x;
    const int n   = blockIdx.z;
    const int o0  = blockIdx.y * TO;
    const int m0  = blockIdx.x * TM;

    const float* xn = x + (size_t)n * A_CH * HW + m0;

    // ---- A (W) staging map: o = tid>>2 (0..127), k8 = (tid&3)*8.
    // 4 lanes cover 128B contiguous per row. One b128 LDS write per thread.
    const int ao = tid >> 2;
    const int ak = (tid & 3) * 8;
    const float* arow = nullptr;
    {
        int R = o0 + ao;
        if (R < O_POSE)     arow = Wp + (size_t)R * A_CH + ak;
        else if (R < O_TOT) arow = Wa + (size_t)(R - O_POSE) * A_CH + ak;
    }
    // ---- B (x) staging map: m = tid&255, k-half = (tid>>8)*16.
    // 16 dword loads (64 consecutive m per wave -> coalesced); two b128 LDS
    // writes; 8-lane groups tile all 32 banks exactly once -> conflict-free.
    const int bm = tid & 255;
    const int bk = (tid >> 8) * 16;
    const float* bbase = xn + (size_t)bk * HW + bm;

    float4 a0, a1;
    float  breg[16];

    auto load_tiles = [&](int k0) {
        if (arow) {
            a0 = *(const float4*)(arow + k0);
            a1 = *(const float4*)(arow + k0 + 4);
        } else {
            a0 = make_float4(0.f, 0.f, 0.f, 0.f);
            a1 = a0;
        }
#pragma unroll
        for (int j = 0; j < 16; ++j)
            breg[j] = bbase[(size_t)(k0 + j) * HW];
    };

    const int aswz = 8 * ((ao >> 1) & 3);
    const int bswz = 8 * ((bm >> 1) & 3);

    auto store_tiles = [&](int buf) {
        short8 av;
        ((unsigned*)&av)[0] = pk(a0.x, a0.y);
        ((unsigned*)&av)[1] = pk(a0.z, a0.w);
        ((unsigned*)&av)[2] = pk(a1.x, a1.y);
        ((unsigned*)&av)[3] = pk(a1.z, a1.w);
        *(short8*)&ldsA[buf][ao * BK + (ak ^ aswz)] = av;

        short8 b0, b1;
#pragma unroll
        for (int j = 0; j < 4; ++j) {
            ((unsigned*)&b0)[j] = pk(breg[2 * j], breg[2 * j + 1]);
            ((unsigned*)&b1)[j] = pk(breg[8 + 2 * j], breg[9 + 2 * j]);
        }
        *(short8*)&ldsB[buf][bm * BK + (bk ^ bswz)]       = b0;
        *(short8*)&ldsB[buf][bm * BK + ((bk + 8) ^ bswz)] = b1;
    };

    // ---- wave -> 64(o) x 64(m) quadrant of the 128x256 tile
    const int lane = tid & 63;
    const int w    = tid >> 6;
    const int wo   = (w >> 2) * 64;
    const int wm   = (w & 3) * 64;
    const int l16  = lane & 15;
    const int g    = lane >> 4;

    f32x4 acc[4][4] = {};  // [fo][fm]

    load_tiles(0);
    store_tiles(0);
    __syncthreads();

    for (int it = 0; it < NIT; ++it) {
        const int cur = it & 1;
        short8 aF[4], bF[4];
#pragma unroll
        for (int f = 0; f < 4; ++f) {
            int r = wo + f * 16 + l16;
            aF[f] = *(const short8*)&ldsA[cur][r * BK + ((g * 8) ^ (8 * ((r >> 1) & 3)))];
            int c = wm + f * 16 + l16;
            bF[f] = *(const short8*)&ldsB[cur][c * BK + ((g * 8) ^ (8 * ((c >> 1) & 3)))];
        }
        if (it + 1 < NIT) load_tiles((it + 1) * BK);  // latency overlaps MFMAs
#pragma unroll
        for (int fo = 0; fo < 4; ++fo)
#pragma unroll
            for (int fm = 0; fm < 4; ++fm)
                acc[fo][fm] = __builtin_amdgcn_mfma_f32_16x16x32_bf16(
                    aF[fo], bF[fm], acc[fo][fm], 0, 0, 0);
        if (it + 1 < NIT) store_tiles(cur ^ 1);
        __syncthreads();   // single barrier per iter (dbuf makes it safe)
    }

    // ---- epilogue: C/D layout col = lane&15, row = (lane>>4)*4 + reg
    float* actOut = out + (size_t)N_B * O_POSE * HW;
    const size_t poseN = (size_t)n * O_POSE * HW;
    const size_t actN  = (size_t)n * O_ACT * HW;
#pragma unroll
    for (int fo = 0; fo < 4; ++fo) {
#pragma unroll
        for (int i = 0; i < 4; ++i) {
            int R = o0 + wo + fo * 16 + g * 4 + i;
            if (R >= O_TOT) continue;
            if (R < O_POSE) {
                float bias = bp[R];
#pragma unroll
                for (int fm = 0; fm < 4; ++fm) {
                    int cc = m0 + wm + fm * 16 + l16;
                    __builtin_nontemporal_store(acc[fo][fm][i] + bias,
                                                &out[poseN + (size_t)R * HW + cc]);
                }
            } else {
                float bias = ba[R - O_POSE];
#pragma unroll
                for (int fm = 0; fm < 4; ++fm) {
                    int cc = m0 + wm + fm * 16 + l16;
                    float v = acc[fo][fm][i] + bias;
                    __builtin_nontemporal_store(1.0f / (1.0f + __expf(-v)),
                                                &actOut[actN + (size_t)(R - O_POSE) * HW + cc]);
                }
            }
        }
    }
}

extern "C" void kernel_launch(void* const* d_in, const int* in_sizes, int n_in,
                              void* d_out, int out_size, void* d_ws, size_t ws_size,
                              hipStream_t stream) {
    (void)in_sizes; (void)n_in; (void)d_ws; (void)ws_size; (void)out_size;
    const float* x  = (const float*)d_in[0];
    const float* Wp = (const float*)d_in[1];
    const float* bp = (const float*)d_in[2];
    const float* Wa = (const float*)d_in[3];
    const float* ba = (const float*)d_in[4];
    dim3 grid(HW / TM, (O_TOT + TO - 1) / TO, N_B);  // (4, 5, 64)
    caps_fused_gemm<<<grid, dim3(512), 0, stream>>>(x, Wp, bp, Wa, ba, (float*)d_out);
}